// Round 4
// baseline (326.643 us; speedup 1.0000x reference)
//
#include <hip/hip_runtime.h>
#include <hip/hip_bf16.h>
#include <stdint.h>

#define HH 128
#define WW 128
#define CC 80
#define HW (HH * WW)
#define BB 32
#define TOPK 100
#define NTHREADS 256
#define SCORE_THR 0.3f
#define NMS_IOU 0.3f
#define BUF 512
// smallest uint bit pattern with float > 0.3f  (bits(0.3f)=0x3E99999A)
#define MINT 0x3E99999Bu

// ---------------------------------------------------------------------------
// Kernel A: peak-NMS + cross-channel max/argmax. NO LDS, NO barriers.
// Grid: 32 batches x 16 stripes = 512 blocks, 256 threads.
// Thread owns a 1-row x 4-col strip: per channel, 3 float4 loads (rows
// y-1,y,y+1; vertical overlap served by L1), horizontal neighbors via 2 lane
// shuffles. Clamp padding == -inf padding for 3x3 max-pool. The barrier-free
// structure lets the compiler software-pipeline loads across channels
// (rounds 2/3 showed __syncthreads+global_load_lds forces vmcnt(0) drain).
// ---------------------------------------------------------------------------
__global__ __launch_bounds__(NTHREADS, 2)
void heat_reduce(const float* __restrict__ hm,
                 float* __restrict__ conf_out,
                 unsigned char* __restrict__ cls_out) {
    const int stripe = blockIdx.x & 15;
    const int b      = blockIdx.x >> 4;
    const int tid    = threadIdx.x;
    const int c31    = tid & 31;
    const int r      = tid >> 5;              // 0..7 row within stripe
    const int x4     = c31 << 2;              // 0,4,...,124
    const int y      = stripe * 8 + r;
    const int yM     = (y > 0) ? y - 1 : 0;
    const int yP     = (y < HH - 1) ? y + 1 : y;
    const bool leftClamp  = (c31 == 0);
    const bool rightClamp = (c31 == 31);

    const float* bbase = hm + (size_t)b * CC * HW;
    const size_t o0 = (size_t)yM * WW + x4;
    const size_t o1 = (size_t)y  * WW + x4;
    const size_t o2 = (size_t)yP * WW + x4;

    float conf[4] = {0.f, 0.f, 0.f, 0.f};
    int   cls[4]  = {0, 0, 0, 0};

    auto rowmax = [&](float4 a, float rm[4]) {
        float le = __shfl_up(a.w, 1, 64);
        float re = __shfl_down(a.x, 1, 64);
        if (leftClamp)  le = a.x;             // clamp == -inf for max-pool
        if (rightClamp) re = a.w;
        rm[0] = fmaxf(fmaxf(le,  a.x), a.y);
        rm[1] = fmaxf(fmaxf(a.x, a.y), a.z);
        rm[2] = fmaxf(fmaxf(a.y, a.z), a.w);
        rm[3] = fmaxf(fmaxf(a.z, a.w), re);
    };

#pragma unroll 8
    for (int c = 0; c < CC; ++c) {
        const float* p = bbase + (size_t)c * HW;
        float4 a0 = *(const float4*)(p + o0);
        float4 a1 = *(const float4*)(p + o1);
        float4 a2 = *(const float4*)(p + o2);
        float rm0[4], rm1[4], rm2[4];
        rowmax(a0, rm0);
        rowmax(a1, rm1);
        rowmax(a2, rm2);
        float ctr[4] = {a1.x, a1.y, a1.z, a1.w};
#pragma unroll
        for (int i = 0; i < 4; ++i) {
            float pool = fmaxf(fmaxf(rm0[i], rm1[i]), rm2[i]);
            float heat = (ctr[i] == pool) ? ctr[i] : 0.0f;
            if (heat > conf[i]) { conf[i] = heat; cls[i] = c; }
        }
    }

    size_t idx = (size_t)b * HW + (size_t)y * WW + x4;
    *(float4*)&conf_out[idx] =
        make_float4(conf[0], conf[1], conf[2], conf[3]);
    uchar4 cv = make_uchar4((unsigned char)cls[0], (unsigned char)cls[1],
                            (unsigned char)cls[2], (unsigned char)cls[3]);
    *(uchar4*)&cls_out[idx] = cv;
}

// ---------------------------------------------------------------------------
// Kernel B: exact top-100 (register-resident binary search on score bits),
// bitonic sort w/ index tie-break, wave0-resident greedy per-class NMS,
// decode + output. Grid: 32 blocks (one per batch), 256 threads.
// Gather phase now reads only 64 KB/block (merged scores).
// ---------------------------------------------------------------------------
__global__ __launch_bounds__(NTHREADS, 1)
void select_nms(const float* __restrict__ conf_m,
                const unsigned char* __restrict__ cls_m,
                const float* __restrict__ wh,
                const float* __restrict__ offset,
                float* __restrict__ out) {
    const int b    = blockIdx.x;
    const int tid  = threadIdx.x;
    const int lane = tid & 63;
    const int wid  = tid >> 6;
    constexpr int VALS = HW / NTHREADS;   // 64

    __shared__ int wsum[4];
    __shared__ unsigned int sCnt;
    __shared__ unsigned long long keys[BUF];

    // ---- load merged scores into registers (thresholded bit patterns) ----
    unsigned u[VALS];
#pragma unroll
    for (int k = 0; k < VALS; ++k) {
        int i = k * NTHREADS + tid;
        float best = conf_m[(size_t)b * HW + i];
        u[k] = (best > SCORE_THR) ? __float_as_uint(best) : 0u;
    }

    auto blockCount = [&](unsigned T) -> int {
        int c = 0;
#pragma unroll
        for (int k = 0; k < VALS; ++k) c += (u[k] >= T);
        for (int o = 32; o > 0; o >>= 1) c += __shfl_down(c, o, 64);
        if (lane == 0) wsum[wid] = c;
        __syncthreads();
        int tot = wsum[0] + wsum[1] + wsum[2] + wsum[3];
        __syncthreads();
        return tot;
    };

    // ---- binary search on uint bits for the 100th-largest score ----
    unsigned V;
    {
        unsigned lo = MINT, hi = 0x3F800001u;   // scores in [0,1)
        int cl = blockCount(lo);
        if (cl < TOPK) {
            V = lo;
        } else {
            while (hi - lo > 1u) {
                unsigned mid = lo + ((hi - lo) >> 1);
                if (blockCount(mid) >= TOPK) lo = mid; else hi = mid;
            }
            V = lo;
        }
    }

    // ---- compact candidates (u >= V) ----
    if (tid == 0) sCnt = 0;
    for (int i = tid; i < BUF; i += NTHREADS) keys[i] = 0ull;
    __syncthreads();
#pragma unroll
    for (int k = 0; k < VALS; ++k) {
        if (u[k] >= V) {
            int i = k * NTHREADS + tid;
            unsigned pos = atomicAdd(&sCnt, 1u);
            if (pos < BUF)
                keys[pos] = ((unsigned long long)u[k] << 32) |
                            (unsigned)(HW - 1 - i);   // tie: lower index first
        }
    }
    __syncthreads();
    int cnt = (int)sCnt;
    if (cnt > BUF) cnt = BUF;

    // ---- bitonic sort (descending), size = next pow2 >= cnt ----
    int n = 1;
    while (n < cnt) n <<= 1;
    for (int k = 2; k <= n; k <<= 1) {
        for (int j = k >> 1; j > 0; j >>= 1) {
            for (int i = tid; i < n; i += NTHREADS) {
                int p = i ^ j;
                if (p > i) {
                    unsigned long long a = keys[i], bb2 = keys[p];
                    bool asc_seg = ((i & k) != 0);
                    bool sw = asc_seg ? (a > bb2) : (a < bb2);
                    if (sw) { keys[i] = bb2; keys[p] = a; }
                }
            }
            __syncthreads();
        }
    }

    // ---- gather top-100 ----
    __shared__ float bx[TOPK][4];
    __shared__ float barea[TOPK];
    __shared__ float bsc[TOPK];
    __shared__ int   bcls[TOPK];
    __shared__ int   keep[TOPK];

    if (tid < TOPK) {
        unsigned long long kk = keys[tid];
        float sc = __uint_as_float((unsigned)(kk >> 32));
        int   i  = HW - 1 - (int)(kk & 0xFFFFFFFFull);
        int   y  = (i >> 7) & 127;
        int   x  = i & 127;
        int   bc = (int)cls_m[(size_t)b * HW + i];

        size_t base = (size_t)b * 2 * HW + (size_t)y * WW + x;
        float ox = offset[base];
        float oy = offset[base + HW];
        float w  = wh[base];
        float hh = wh[base + HW];
        float cx = (float)x + ox;
        float cy = (float)y + oy;
        float x1 = (cx - w  * 0.5f) * (1.0f / 128.0f);
        float y1 = (cy - hh * 0.5f) * (1.0f / 128.0f);
        float x2 = (cx + w  * 0.5f) * (1.0f / 128.0f);
        float y2 = (cy + hh * 0.5f) * (1.0f / 128.0f);
        bx[tid][0] = x1; bx[tid][1] = y1; bx[tid][2] = x2; bx[tid][3] = y2;
        barea[tid] = (x2 - x1) * (y2 - y1);
        bsc[tid]   = sc;
        bcls[tid]  = bc;
        keep[tid]  = (sc > SCORE_THR) ? 1 : 0;
    }
    __syncthreads();

    // ---- greedy per-class NMS: single wave, shuffle broadcasts, 0 barriers --
    if (tid < 64) {
        const int A  = tid;
        const int Bq = tid + 64;
        float aX0 = bx[A][0], aY0 = bx[A][1], aX1 = bx[A][2], aY1 = bx[A][3];
        float aAr = barea[A]; int aC = bcls[A]; int kA = keep[A];
        float bX0 = 0, bY0 = 0, bX1 = 0, bY1 = 0, bAr = 0;
        int   bC = -1, kB = 0;
        if (Bq < TOPK) {
            bX0 = bx[Bq][0]; bY0 = bx[Bq][1]; bX1 = bx[Bq][2]; bY1 = bx[Bq][3];
            bAr = barea[Bq]; bC = bcls[Bq]; kB = keep[Bq];
        }
        for (int i = 0; i < TOPK; ++i) {
            int kv    = (i < 64) ? kA : kB;
            int alive = __shfl(kv, i & 63, 64);
            if (alive) {
                float iX0 = bx[i][0], iY0 = bx[i][1];
                float iX1 = bx[i][2], iY1 = bx[i][3];
                float iAr = barea[i]; int iC = bcls[i];
                if (A > i && aC == iC) {
                    float lx = fmaxf(aX0, iX0), ly = fmaxf(aY0, iY0);
                    float rx = fminf(aX1, iX1), ry = fminf(aY1, iY1);
                    float iw = fmaxf(rx - lx, 0.f), ih = fmaxf(ry - ly, 0.f);
                    float inter = iw * ih;
                    float iou = inter / (aAr + iAr - inter + 1e-9f);
                    if (iou > NMS_IOU) kA = 0;
                }
                if (Bq > i && Bq < TOPK && bC == iC) {
                    float lx = fmaxf(bX0, iX0), ly = fmaxf(bY0, iY0);
                    float rx = fminf(bX1, iX1), ry = fminf(bY1, iY1);
                    float iw = fmaxf(rx - lx, 0.f), ih = fmaxf(ry - ly, 0.f);
                    float inter = iw * ih;
                    float iou = inter / (bAr + iAr - inter + 1e-9f);
                    if (iou > NMS_IOU) kB = 0;
                }
            }
        }
        keep[A] = kA;
        if (Bq < TOPK) keep[Bq] = kB;
    }
    __syncthreads();

    // ---- output [B,100,6]; zero non-kept rows (d_out is poisoned) ----
    for (int t = tid; t < TOPK * 6; t += NTHREADS) {
        int j = t / 6, comp = t - j * 6;
        float v = 0.0f;
        if (keep[j]) {
            if (comp < 4)       v = bx[j][comp] * 512.0f;
            else if (comp == 4) v = bsc[j];
            else                v = (float)bcls[j];
        }
        out[(size_t)b * (TOPK * 6) + t] = v;
    }
}

extern "C" void kernel_launch(void* const* d_in, const int* in_sizes, int n_in,
                              void* d_out, int out_size, void* d_ws, size_t ws_size,
                              hipStream_t stream) {
    const float* hm     = (const float*)d_in[0];
    const float* wh     = (const float*)d_in[1];
    const float* offset = (const float*)d_in[2];
    float* out = (float*)d_out;

    float* confm = (float*)d_ws;                                   // 2 MB
    unsigned char* clsm = (unsigned char*)d_ws + (size_t)BB * HW * 4; // 0.5 MB

    heat_reduce<<<BB * 16, NTHREADS, 0, stream>>>(hm, confm, clsm);
    select_nms<<<BB, NTHREADS, 0, stream>>>(confm, clsm, wh, offset, out);
}

// Round 5
// 292.549 us; speedup vs baseline: 1.1165x; 1.1165x over previous
//
#include <hip/hip_runtime.h>
#include <hip/hip_bf16.h>
#include <stdint.h>

#define HH 128
#define WW 128
#define CC 80
#define HW (HH * WW)
#define BB 32
#define TOPK 100
#define NTHREADS 256
#define SCORE_THR 0.3f
#define NMS_IOU 0.3f
#define BUF 512
#define GG 4
#define PLANE ((size_t)BB * HW)
// smallest uint bit pattern with float > 0.3f  (bits(0.3f)=0x3E99999A)
#define MINT 0x3E99999Bu

// ---------------------------------------------------------------------------
// Kernel A: peak-NMS + per-group channel max/argmax. NO LDS, NO barriers.
// Grid: 32 b x 4 groups x 16 stripes = 2048 blocks (8 blocks/CU, 32 waves/CU),
// 256 threads. Thread owns 1 row x 4 cols; per channel: 3 float4 loads
// (vertical halo via L1/L2), horizontal neighbors via 2 lane shuffles.
// EXPLICIT 1-deep register prefetch: next channel's loads issue before this
// channel's compute (round 4 showed the compiler won't pipeline on its own:
// VGPR=24). Clamp padding == -inf padding for 3x3 max-pool.
// Partials written PLANAR [G][B*HW] for coalescing both here and in select.
// ---------------------------------------------------------------------------
__global__ __launch_bounds__(NTHREADS, 8)
void heat_reduce(const float* __restrict__ hm,
                 float* __restrict__ conf_part,
                 unsigned char* __restrict__ cls_part) {
    constexpr int CPG = CC / GG;              // 20
    const int stripe = blockIdx.x & 15;       // fastest: adjacent stripes share halo rows in L2
    const int g      = (blockIdx.x >> 4) & 3;
    const int b      = blockIdx.x >> 6;
    const int tid    = threadIdx.x;
    const int c31    = tid & 31;
    const int r      = tid >> 5;              // 0..7 row within stripe
    const int x4     = c31 << 2;              // 0,4,...,124
    const int y      = stripe * 8 + r;
    const int yM     = (y > 0) ? y - 1 : 0;
    const int yP     = (y < HH - 1) ? y + 1 : y;
    const bool leftClamp  = (c31 == 0);
    const bool rightClamp = (c31 == 31);
    const int c0     = g * CPG;

    const float* p0 = hm + (size_t)(b * CC + c0) * HW + (size_t)yM * WW + x4;
    const float* p1 = hm + (size_t)(b * CC + c0) * HW + (size_t)y  * WW + x4;
    const float* p2 = hm + (size_t)(b * CC + c0) * HW + (size_t)yP * WW + x4;

    float conf[4] = {0.f, 0.f, 0.f, 0.f};
    int   cls[4]  = {c0, c0, c0, c0};

    auto rowmax = [&](float4 a, float rm[4]) {
        float le = __shfl_up(a.w, 1, 64);
        float re = __shfl_down(a.x, 1, 64);
        if (leftClamp)  le = a.x;             // clamp == -inf for max-pool
        if (rightClamp) re = a.w;
        rm[0] = fmaxf(fmaxf(le,  a.x), a.y);
        rm[1] = fmaxf(fmaxf(a.x, a.y), a.z);
        rm[2] = fmaxf(fmaxf(a.y, a.z), a.w);
        rm[3] = fmaxf(fmaxf(a.z, a.w), re);
    };

    // explicit 1-deep prefetch pipeline
    float4 n0 = *(const float4*)p0;
    float4 n1 = *(const float4*)p1;
    float4 n2 = *(const float4*)p2;

    for (int cc = 0; cc < CPG; ++cc) {
        float4 a0 = n0, a1 = n1, a2 = n2;
        if (cc + 1 < CPG) {
            p0 += HW; p1 += HW; p2 += HW;
            n0 = *(const float4*)p0;
            n1 = *(const float4*)p1;
            n2 = *(const float4*)p2;
        }
        float rm0[4], rm1[4], rm2[4];
        rowmax(a0, rm0);
        rowmax(a1, rm1);
        rowmax(a2, rm2);
        float ctr[4] = {a1.x, a1.y, a1.z, a1.w};
        const int c = c0 + cc;
#pragma unroll
        for (int i = 0; i < 4; ++i) {
            float pool = fmaxf(fmaxf(rm0[i], rm1[i]), rm2[i]);
            float heat = (ctr[i] == pool) ? ctr[i] : 0.0f;
            if (heat > conf[i]) { conf[i] = heat; cls[i] = c; }
        }
    }

    size_t idx = (size_t)g * PLANE + (size_t)b * HW + (size_t)y * WW + x4;
    *(float4*)&conf_part[idx] = make_float4(conf[0], conf[1], conf[2], conf[3]);
    *(uchar4*)&cls_part[idx]  = make_uchar4((unsigned char)cls[0],
                                            (unsigned char)cls[1],
                                            (unsigned char)cls[2],
                                            (unsigned char)cls[3]);
}

// ---------------------------------------------------------------------------
// Kernel B: merge planar partials, exact top-100 (register-resident binary
// search on score bits), bitonic sort w/ index tie-break, wave0-resident
// greedy per-class NMS, decode + output. Grid: 32 blocks, 256 threads.
// ---------------------------------------------------------------------------
__global__ __launch_bounds__(NTHREADS, 1)
void select_nms(const float* __restrict__ conf_part,
                const unsigned char* __restrict__ cls_part,
                const float* __restrict__ wh,
                const float* __restrict__ offset,
                float* __restrict__ out) {
    const int b    = blockIdx.x;
    const int tid  = threadIdx.x;
    const int lane = tid & 63;
    const int wid  = tid >> 6;
    constexpr int VALS = HW / NTHREADS;   // 64

    __shared__ int wsum[4];
    __shared__ unsigned int sCnt;
    __shared__ unsigned long long keys[BUF];

    // ---- merge planar partials into registers (thresholded score bits) ----
    unsigned u[VALS];
#pragma unroll
    for (int k = 0; k < VALS; ++k) {
        size_t base = (size_t)b * HW + (k * NTHREADS + tid);
        float s0 = conf_part[base];
        float s1 = conf_part[PLANE + base];
        float s2 = conf_part[2 * PLANE + base];
        float s3 = conf_part[3 * PLANE + base];
        float best = fmaxf(fmaxf(s0, s1), fmaxf(s2, s3));
        u[k] = (best > SCORE_THR) ? __float_as_uint(best) : 0u;
    }

    auto blockCount = [&](unsigned T) -> int {
        int c = 0;
#pragma unroll
        for (int k = 0; k < VALS; ++k) c += (u[k] >= T);
        for (int o = 32; o > 0; o >>= 1) c += __shfl_down(c, o, 64);
        if (lane == 0) wsum[wid] = c;
        __syncthreads();
        int tot = wsum[0] + wsum[1] + wsum[2] + wsum[3];
        __syncthreads();
        return tot;
    };

    // ---- binary search on uint bits for the 100th-largest score ----
    unsigned V;
    {
        unsigned lo = MINT, hi = 0x3F800001u;   // scores in [0,1)
        int cl = blockCount(lo);
        if (cl < TOPK) {
            V = lo;
        } else {
            while (hi - lo > 1u) {
                unsigned mid = lo + ((hi - lo) >> 1);
                if (blockCount(mid) >= TOPK) lo = mid; else hi = mid;
            }
            V = lo;
        }
    }

    // ---- compact candidates (u >= V) ----
    if (tid == 0) sCnt = 0;
    for (int i = tid; i < BUF; i += NTHREADS) keys[i] = 0ull;
    __syncthreads();
#pragma unroll
    for (int k = 0; k < VALS; ++k) {
        if (u[k] >= V) {
            int i = k * NTHREADS + tid;
            unsigned pos = atomicAdd(&sCnt, 1u);
            if (pos < BUF)
                keys[pos] = ((unsigned long long)u[k] << 32) |
                            (unsigned)(HW - 1 - i);   // tie: lower index first
        }
    }
    __syncthreads();
    int cnt = (int)sCnt;
    if (cnt > BUF) cnt = BUF;

    // ---- bitonic sort (descending), size = next pow2 >= cnt ----
    int n = 1;
    while (n < cnt) n <<= 1;
    for (int k = 2; k <= n; k <<= 1) {
        for (int j = k >> 1; j > 0; j >>= 1) {
            for (int i = tid; i < n; i += NTHREADS) {
                int p = i ^ j;
                if (p > i) {
                    unsigned long long a = keys[i], bb2 = keys[p];
                    bool asc_seg = ((i & k) != 0);
                    bool sw = asc_seg ? (a > bb2) : (a < bb2);
                    if (sw) { keys[i] = bb2; keys[p] = a; }
                }
            }
            __syncthreads();
        }
    }

    // ---- gather top-100 ----
    __shared__ float bx[TOPK][4];
    __shared__ float barea[TOPK];
    __shared__ float bsc[TOPK];
    __shared__ int   bcls[TOPK];
    __shared__ int   keep[TOPK];

    if (tid < TOPK) {
        unsigned long long kk = keys[tid];
        float sc = __uint_as_float((unsigned)(kk >> 32));
        int   i  = HW - 1 - (int)(kk & 0xFFFFFFFFull);
        int   y  = (i >> 7) & 127;
        int   x  = i & 127;
        // merged class: group-ascending strict > == global first-index argmax
        // (groups are contiguous ascending channel ranges)
        size_t base0 = (size_t)b * HW + i;
        float bcf = conf_part[base0];
        int   bc  = (int)cls_part[base0];
#pragma unroll
        for (int gg = 1; gg < GG; ++gg) {
            float cf = conf_part[gg * PLANE + base0];
            if (cf > bcf) { bcf = cf; bc = (int)cls_part[gg * PLANE + base0]; }
        }

        size_t base = (size_t)b * 2 * HW + (size_t)y * WW + x;
        float ox = offset[base];
        float oy = offset[base + HW];
        float w  = wh[base];
        float hh = wh[base + HW];
        float cx = (float)x + ox;
        float cy = (float)y + oy;
        float x1 = (cx - w  * 0.5f) * (1.0f / 128.0f);
        float y1 = (cy - hh * 0.5f) * (1.0f / 128.0f);
        float x2 = (cx + w  * 0.5f) * (1.0f / 128.0f);
        float y2 = (cy + hh * 0.5f) * (1.0f / 128.0f);
        bx[tid][0] = x1; bx[tid][1] = y1; bx[tid][2] = x2; bx[tid][3] = y2;
        barea[tid] = (x2 - x1) * (y2 - y1);
        bsc[tid]   = sc;
        bcls[tid]  = bc;
        keep[tid]  = (sc > SCORE_THR) ? 1 : 0;
    }
    __syncthreads();

    // ---- greedy per-class NMS: single wave, shuffle broadcasts, 0 barriers --
    if (tid < 64) {
        const int A  = tid;
        const int Bq = tid + 64;
        float aX0 = bx[A][0], aY0 = bx[A][1], aX1 = bx[A][2], aY1 = bx[A][3];
        float aAr = barea[A]; int aC = bcls[A]; int kA = keep[A];
        float bX0 = 0, bY0 = 0, bX1 = 0, bY1 = 0, bAr = 0;
        int   bC = -1, kB = 0;
        if (Bq < TOPK) {
            bX0 = bx[Bq][0]; bY0 = bx[Bq][1]; bX1 = bx[Bq][2]; bY1 = bx[Bq][3];
            bAr = barea[Bq]; bC = bcls[Bq]; kB = keep[Bq];
        }
        for (int i = 0; i < TOPK; ++i) {
            int kv    = (i < 64) ? kA : kB;
            int alive = __shfl(kv, i & 63, 64);
            if (alive) {
                float iX0 = bx[i][0], iY0 = bx[i][1];
                float iX1 = bx[i][2], iY1 = bx[i][3];
                float iAr = barea[i]; int iC = bcls[i];
                if (A > i && aC == iC) {
                    float lx = fmaxf(aX0, iX0), ly = fmaxf(aY0, iY0);
                    float rx = fminf(aX1, iX1), ry = fminf(aY1, iY1);
                    float iw = fmaxf(rx - lx, 0.f), ih = fmaxf(ry - ly, 0.f);
                    float inter = iw * ih;
                    float iou = inter / (aAr + iAr - inter + 1e-9f);
                    if (iou > NMS_IOU) kA = 0;
                }
                if (Bq > i && Bq < TOPK && bC == iC) {
                    float lx = fmaxf(bX0, iX0), ly = fmaxf(bY0, iY0);
                    float rx = fminf(bX1, iX1), ry = fminf(bY1, iY1);
                    float iw = fmaxf(rx - lx, 0.f), ih = fmaxf(ry - ly, 0.f);
                    float inter = iw * ih;
                    float iou = inter / (bAr + iAr - inter + 1e-9f);
                    if (iou > NMS_IOU) kB = 0;
                }
            }
        }
        keep[A] = kA;
        if (Bq < TOPK) keep[Bq] = kB;
    }
    __syncthreads();

    // ---- output [B,100,6]; zero non-kept rows (d_out is poisoned) ----
    for (int t = tid; t < TOPK * 6; t += NTHREADS) {
        int j = t / 6, comp = t - j * 6;
        float v = 0.0f;
        if (keep[j]) {
            if (comp < 4)       v = bx[j][comp] * 512.0f;
            else if (comp == 4) v = bsc[j];
            else                v = (float)bcls[j];
        }
        out[(size_t)b * (TOPK * 6) + t] = v;
    }
}

extern "C" void kernel_launch(void* const* d_in, const int* in_sizes, int n_in,
                              void* d_out, int out_size, void* d_ws, size_t ws_size,
                              hipStream_t stream) {
    const float* hm     = (const float*)d_in[0];
    const float* wh     = (const float*)d_in[1];
    const float* offset = (const float*)d_in[2];
    float* out = (float*)d_out;

    float* confp = (float*)d_ws;                                // 8 MB planar
    unsigned char* clsp = (unsigned char*)d_ws + GG * PLANE * 4; // 2 MB planar

    heat_reduce<<<BB * GG * 16, NTHREADS, 0, stream>>>(hm, confp, clsp);
    select_nms<<<BB, NTHREADS, 0, stream>>>(confp, clsp, wh, offset, out);
}

// Round 6
// 292.256 us; speedup vs baseline: 1.1177x; 1.0010x over previous
//
#include <hip/hip_runtime.h>
#include <hip/hip_bf16.h>
#include <stdint.h>

#define HH 128
#define WW 128
#define CC 80
#define HW (HH * WW)
#define BB 32
#define TOPK 100
#define NTHREADS 256
#define SCORE_THR 0.3f
#define NMS_IOU 0.3f
#define BUF 512
#define GG 4
#define PLANE ((size_t)BB * HW)
// smallest uint bit pattern with float > 0.3f  (bits(0.3f)=0x3E99999A)
#define MINT 0x3E99999Bu

// ---------------------------------------------------------------------------
// Kernel A: peak-NMS + per-group channel max/argmax. NO LDS, NO barriers.
// Grid: 32 b x 4 groups x 16 stripes = 2048 blocks, 256 threads.
// Round-6 change: SGPR-base addressing. One uniform channel pointer (scalar
// add per channel) + three loop-invariant 32-bit lane offsets -> loads become
// global_load_dwordx4 v, voff, s[base] with zero per-lane 64-bit math.
// Cuts ~20 VALU/channel and ~9 VGPRs vs round 5 (goal: fit 64 VGPR so
// launch_bounds(256,8) delivers real 8 blocks/CU).
// Explicit 1-deep register prefetch; clamp pad == -inf pad for 3x3 max-pool.
// ---------------------------------------------------------------------------
__global__ __launch_bounds__(NTHREADS, 8)
void heat_reduce(const float* __restrict__ hm,
                 float* __restrict__ conf_part,
                 unsigned char* __restrict__ cls_part) {
    constexpr int CPG = CC / GG;              // 20
    const int stripe = blockIdx.x & 15;
    const int g      = (blockIdx.x >> 4) & 3;
    const int b      = blockIdx.x >> 6;
    const int tid    = threadIdx.x;
    const int c31    = tid & 31;
    const int r      = tid >> 5;              // 0..7 row within stripe
    const int x4     = c31 << 2;              // 0,4,...,124
    const int y      = stripe * 8 + r;
    const int yM     = (y > 0) ? y - 1 : 0;
    const int yP     = (y < HH - 1) ? y + 1 : y;
    const bool leftClamp  = (c31 == 0);
    const bool rightClamp = (c31 == 31);
    const int c0     = g * CPG;

    // uniform (SGPR) channel base; thread-varying 32-bit invariant offsets
    const float* cbase = hm + (size_t)(b * CC + c0) * HW;
    const uint o0 = (uint)(yM * WW + x4);
    const uint o1 = (uint)(y  * WW + x4);
    const uint o2 = (uint)(yP * WW + x4);

    float conf[4] = {0.f, 0.f, 0.f, 0.f};
    int   cls[4]  = {c0, c0, c0, c0};

    auto rowmax = [&](float4 a, float rm[4]) {
        float le = __shfl_up(a.w, 1, 64);
        float re = __shfl_down(a.x, 1, 64);
        if (leftClamp)  le = a.x;             // clamp == -inf for max-pool
        if (rightClamp) re = a.w;
        rm[0] = fmaxf(fmaxf(le,  a.x), a.y);
        rm[1] = fmaxf(fmaxf(a.x, a.y), a.z);
        rm[2] = fmaxf(fmaxf(a.y, a.z), a.w);
        rm[3] = fmaxf(fmaxf(a.z, a.w), re);
    };

    // 1-deep register prefetch pipeline
    float4 n0 = *(const float4*)(cbase + o0);
    float4 n1 = *(const float4*)(cbase + o1);
    float4 n2 = *(const float4*)(cbase + o2);

    for (int cc = 0; cc < CPG; ++cc) {
        float4 a0 = n0, a1 = n1, a2 = n2;
        if (cc + 1 < CPG) {
            cbase += HW;                       // scalar add (uniform)
            n0 = *(const float4*)(cbase + o0);
            n1 = *(const float4*)(cbase + o1);
            n2 = *(const float4*)(cbase + o2);
        }
        float rm0[4], rm1[4], rm2[4];
        rowmax(a0, rm0);
        rowmax(a1, rm1);
        rowmax(a2, rm2);
        float ctr[4] = {a1.x, a1.y, a1.z, a1.w};
        const int c = c0 + cc;
#pragma unroll
        for (int i = 0; i < 4; ++i) {
            float pool = fmaxf(fmaxf(rm0[i], rm1[i]), rm2[i]);
            float heat = (ctr[i] == pool) ? ctr[i] : 0.0f;
            if (heat > conf[i]) { conf[i] = heat; cls[i] = c; }
        }
    }

    size_t idx = (size_t)g * PLANE + (size_t)b * HW + (size_t)y * WW + x4;
    *(float4*)&conf_part[idx] = make_float4(conf[0], conf[1], conf[2], conf[3]);
    *(uchar4*)&cls_part[idx]  = make_uchar4((unsigned char)cls[0],
                                            (unsigned char)cls[1],
                                            (unsigned char)cls[2],
                                            (unsigned char)cls[3]);
}

// ---------------------------------------------------------------------------
// Kernel B: UNCHANGED from round 5 (controlled experiment: Dtotal = Dheat).
// Merge planar partials, exact top-100, bitonic sort, wave0 NMS, decode.
// ---------------------------------------------------------------------------
__global__ __launch_bounds__(NTHREADS, 1)
void select_nms(const float* __restrict__ conf_part,
                const unsigned char* __restrict__ cls_part,
                const float* __restrict__ wh,
                const float* __restrict__ offset,
                float* __restrict__ out) {
    const int b    = blockIdx.x;
    const int tid  = threadIdx.x;
    const int lane = tid & 63;
    const int wid  = tid >> 6;
    constexpr int VALS = HW / NTHREADS;   // 64

    __shared__ int wsum[4];
    __shared__ unsigned int sCnt;
    __shared__ unsigned long long keys[BUF];

    // ---- merge planar partials into registers (thresholded score bits) ----
    unsigned u[VALS];
#pragma unroll
    for (int k = 0; k < VALS; ++k) {
        size_t base = (size_t)b * HW + (k * NTHREADS + tid);
        float s0 = conf_part[base];
        float s1 = conf_part[PLANE + base];
        float s2 = conf_part[2 * PLANE + base];
        float s3 = conf_part[3 * PLANE + base];
        float best = fmaxf(fmaxf(s0, s1), fmaxf(s2, s3));
        u[k] = (best > SCORE_THR) ? __float_as_uint(best) : 0u;
    }

    auto blockCount = [&](unsigned T) -> int {
        int c = 0;
#pragma unroll
        for (int k = 0; k < VALS; ++k) c += (u[k] >= T);
        for (int o = 32; o > 0; o >>= 1) c += __shfl_down(c, o, 64);
        if (lane == 0) wsum[wid] = c;
        __syncthreads();
        int tot = wsum[0] + wsum[1] + wsum[2] + wsum[3];
        __syncthreads();
        return tot;
    };

    // ---- binary search on uint bits for the 100th-largest score ----
    unsigned V;
    {
        unsigned lo = MINT, hi = 0x3F800001u;   // scores in [0,1)
        int cl = blockCount(lo);
        if (cl < TOPK) {
            V = lo;
        } else {
            while (hi - lo > 1u) {
                unsigned mid = lo + ((hi - lo) >> 1);
                if (blockCount(mid) >= TOPK) lo = mid; else hi = mid;
            }
            V = lo;
        }
    }

    // ---- compact candidates (u >= V) ----
    if (tid == 0) sCnt = 0;
    for (int i = tid; i < BUF; i += NTHREADS) keys[i] = 0ull;
    __syncthreads();
#pragma unroll
    for (int k = 0; k < VALS; ++k) {
        if (u[k] >= V) {
            int i = k * NTHREADS + tid;
            unsigned pos = atomicAdd(&sCnt, 1u);
            if (pos < BUF)
                keys[pos] = ((unsigned long long)u[k] << 32) |
                            (unsigned)(HW - 1 - i);   // tie: lower index first
        }
    }
    __syncthreads();
    int cnt = (int)sCnt;
    if (cnt > BUF) cnt = BUF;

    // ---- bitonic sort (descending), size = next pow2 >= cnt ----
    int n = 1;
    while (n < cnt) n <<= 1;
    for (int k = 2; k <= n; k <<= 1) {
        for (int j = k >> 1; j > 0; j >>= 1) {
            for (int i = tid; i < n; i += NTHREADS) {
                int p = i ^ j;
                if (p > i) {
                    unsigned long long a = keys[i], bb2 = keys[p];
                    bool asc_seg = ((i & k) != 0);
                    bool sw = asc_seg ? (a > bb2) : (a < bb2);
                    if (sw) { keys[i] = bb2; keys[p] = a; }
                }
            }
            __syncthreads();
        }
    }

    // ---- gather top-100 ----
    __shared__ float bx[TOPK][4];
    __shared__ float barea[TOPK];
    __shared__ float bsc[TOPK];
    __shared__ int   bcls[TOPK];
    __shared__ int   keep[TOPK];

    if (tid < TOPK) {
        unsigned long long kk = keys[tid];
        float sc = __uint_as_float((unsigned)(kk >> 32));
        int   i  = HW - 1 - (int)(kk & 0xFFFFFFFFull);
        int   y  = (i >> 7) & 127;
        int   x  = i & 127;
        // merged class: group-ascending strict > == global first-index argmax
        size_t base0 = (size_t)b * HW + i;
        float bcf = conf_part[base0];
        int   bc  = (int)cls_part[base0];
#pragma unroll
        for (int gg = 1; gg < GG; ++gg) {
            float cf = conf_part[gg * PLANE + base0];
            if (cf > bcf) { bcf = cf; bc = (int)cls_part[gg * PLANE + base0]; }
        }

        size_t base = (size_t)b * 2 * HW + (size_t)y * WW + x;
        float ox = offset[base];
        float oy = offset[base + HW];
        float w  = wh[base];
        float hh = wh[base + HW];
        float cx = (float)x + ox;
        float cy = (float)y + oy;
        float x1 = (cx - w  * 0.5f) * (1.0f / 128.0f);
        float y1 = (cy - hh * 0.5f) * (1.0f / 128.0f);
        float x2 = (cx + w  * 0.5f) * (1.0f / 128.0f);
        float y2 = (cy + hh * 0.5f) * (1.0f / 128.0f);
        bx[tid][0] = x1; bx[tid][1] = y1; bx[tid][2] = x2; bx[tid][3] = y2;
        barea[tid] = (x2 - x1) * (y2 - y1);
        bsc[tid]   = sc;
        bcls[tid]  = bc;
        keep[tid]  = (sc > SCORE_THR) ? 1 : 0;
    }
    __syncthreads();

    // ---- greedy per-class NMS: single wave, shuffle broadcasts, 0 barriers --
    if (tid < 64) {
        const int A  = tid;
        const int Bq = tid + 64;
        float aX0 = bx[A][0], aY0 = bx[A][1], aX1 = bx[A][2], aY1 = bx[A][3];
        float aAr = barea[A]; int aC = bcls[A]; int kA = keep[A];
        float bX0 = 0, bY0 = 0, bX1 = 0, bY1 = 0, bAr = 0;
        int   bC = -1, kB = 0;
        if (Bq < TOPK) {
            bX0 = bx[Bq][0]; bY0 = bx[Bq][1]; bX1 = bx[Bq][2]; bY1 = bx[Bq][3];
            bAr = barea[Bq]; bC = bcls[Bq]; kB = keep[Bq];
        }
        for (int i = 0; i < TOPK; ++i) {
            int kv    = (i < 64) ? kA : kB;
            int alive = __shfl(kv, i & 63, 64);
            if (alive) {
                float iX0 = bx[i][0], iY0 = bx[i][1];
                float iX1 = bx[i][2], iY1 = bx[i][3];
                float iAr = barea[i]; int iC = bcls[i];
                if (A > i && aC == iC) {
                    float lx = fmaxf(aX0, iX0), ly = fmaxf(aY0, iY0);
                    float rx = fminf(aX1, iX1), ry = fminf(aY1, iY1);
                    float iw = fmaxf(rx - lx, 0.f), ih = fmaxf(ry - ly, 0.f);
                    float inter = iw * ih;
                    float iou = inter / (aAr + iAr - inter + 1e-9f);
                    if (iou > NMS_IOU) kA = 0;
                }
                if (Bq > i && Bq < TOPK && bC == iC) {
                    float lx = fmaxf(bX0, iX0), ly = fmaxf(bY0, iY0);
                    float rx = fminf(bX1, iX1), ry = fminf(bY1, iY1);
                    float iw = fmaxf(rx - lx, 0.f), ih = fmaxf(ry - ly, 0.f);
                    float inter = iw * ih;
                    float iou = inter / (bAr + iAr - inter + 1e-9f);
                    if (iou > NMS_IOU) kB = 0;
                }
            }
        }
        keep[A] = kA;
        if (Bq < TOPK) keep[Bq] = kB;
    }
    __syncthreads();

    // ---- output [B,100,6]; zero non-kept rows (d_out is poisoned) ----
    for (int t = tid; t < TOPK * 6; t += NTHREADS) {
        int j = t / 6, comp = t - j * 6;
        float v = 0.0f;
        if (keep[j]) {
            if (comp < 4)       v = bx[j][comp] * 512.0f;
            else if (comp == 4) v = bsc[j];
            else                v = (float)bcls[j];
        }
        out[(size_t)b * (TOPK * 6) + t] = v;
    }
}

extern "C" void kernel_launch(void* const* d_in, const int* in_sizes, int n_in,
                              void* d_out, int out_size, void* d_ws, size_t ws_size,
                              hipStream_t stream) {
    const float* hm     = (const float*)d_in[0];
    const float* wh     = (const float*)d_in[1];
    const float* offset = (const float*)d_in[2];
    float* out = (float*)d_out;

    float* confp = (float*)d_ws;                                 // 8 MB planar
    unsigned char* clsp = (unsigned char*)d_ws + GG * PLANE * 4; // 2 MB planar

    heat_reduce<<<BB * GG * 16, NTHREADS, 0, stream>>>(hm, confp, clsp);
    select_nms<<<BB, NTHREADS, 0, stream>>>(confp, clsp, wh, offset, out);
}